// Round 1
// baseline (34.122 us; speedup 1.0000x reference)
//
#include <hip/hip_runtime.h>
#include <math.h>

#define HN   512
#define N2M  32
#define LVAL 8192
#define CHUNK 16
#define TPB  256

// One block per (l-tile, h). First 32 threads compute per-mode params into LDS,
// then every thread evaluates CHUNK consecutive l values for all 32 modes via
// exact chunk-start (exp + hi/lo-split revolution phase) + complex recurrence.
__global__ __launch_bounds__(TPB) void s4d_main(
    const float* __restrict__ log_dt,
    const float* __restrict__ B_real,
    const float* __restrict__ B_imag,
    const float* __restrict__ Cmat,
    const float* __restrict__ A_real,
    const float* __restrict__ A_imag,
    float* __restrict__ out)
{
    __shared__ float sp[N2M * 8];
    const int h = blockIdx.y;
    const int t = threadIdx.x;

    if (t < N2M) {
        const int idx = h * N2M + t;
        const float dt  = expf(log_dt[h]);
        const float Are = -expf(A_real[idx]) - 1e-6f;
        const float Aim = A_imag[idx];
        const float hdt = 0.5f * dt;
        // denom = 1 - dt*A/2 + 1e-6
        const float dre = 1.0f - hdt * Are + 1e-6f;
        const float dim_ = -hdt * Aim;
        // num = 1 + dt*A/2
        const float nre = 1.0f + hdt * Are;
        const float nim = hdt * Aim;
        const float inv = 1.0f / (dre * dre + dim_ * dim_);
        // z = dtA = num / denom
        const float zr = (nre * dre + nim * dim_) * inv;
        const float zi = (nim * dre - nre * dim_) * inv;
        // dtB = dt * B / denom ; c2 = 2*C*dtB
        const float br = B_real[idx], bi = B_imag[idx];
        const float tbr = dt * ((br * dre + bi * dim_) * inv);
        const float tbi = dt * ((bi * dre - br * dim_) * inv);
        const float Cv = Cmat[idx];
        const float c2r = 2.0f * Cv * tbr;
        const float c2i = 2.0f * Cv * tbi;
        // log z: xr = log|z| ; phase in REVOLUTIONS, split hi/lo so that
        // l0 * phi_hi is exact in f32 (l0 < 2^13, phi_hi has 11 sig bits).
        const float xr  = 0.5f * logf(zr * zr + zi * zi);
        const float phi = atan2f(zi, zr) * 0.15915494309189535f;
        const float phi_hi = __uint_as_float(__float_as_uint(phi) & 0xFFFFE000u);
        const float phi_lo = phi - phi_hi;
        sp[t * 8 + 0] = zr;
        sp[t * 8 + 1] = zi;
        sp[t * 8 + 2] = xr;
        sp[t * 8 + 3] = phi_hi;
        sp[t * 8 + 4] = phi_lo;
        sp[t * 8 + 5] = c2r;
        sp[t * 8 + 6] = c2i;
        sp[t * 8 + 7] = 0.0f;
    }
    __syncthreads();

    const int l0 = blockIdx.x * (TPB * CHUNK) + t * CHUNK;
    const float l0f = (float)l0;

    float acc[CHUNK];
#pragma unroll
    for (int j = 0; j < CHUNK; ++j) acc[j] = 0.0f;

#pragma unroll 4
    for (int n = 0; n < N2M; ++n) {
        const float zr = sp[n * 8 + 0];
        const float zi = sp[n * 8 + 1];
        const float xr = sp[n * 8 + 2];
        const float ph = sp[n * 8 + 3];
        const float pl = sp[n * 8 + 4];
        const float cr = sp[n * 8 + 5];
        const float ci = sp[n * 8 + 6];

        // |z|^l0
        const float e = __expf(l0f * xr);
        // phase(l0) in revolutions, exactly range-reduced
        const float p   = l0f * ph;          // exact (24-bit product)
        const float f1  = p - floorf(p);     // exact fractional part
        float rev = fmaf(l0f, pl, f1);
        rev = rev - floorf(rev);             // [0,1)
        const float ang = rev * 6.283185307179586f;
        const float sn = __sinf(ang);
        const float cs = __cosf(ang);

        // u = c2 * z^l0
        float ur = e * (cr * cs - ci * sn);
        float ui = e * (cr * sn + ci * cs);

#pragma unroll
        for (int j = 0; j < CHUNK; ++j) {
            acc[j] += ur;
            const float nur = ur * zr - ui * zi;
            ui = fmaf(ur, zi, ui * zr);
            ur = nur;
        }
    }

    float4* o = (float4*)(out + (size_t)h * LVAL + l0);
#pragma unroll
    for (int j = 0; j < CHUNK / 4; ++j) {
        o[j] = make_float4(acc[4 * j + 0], acc[4 * j + 1],
                           acc[4 * j + 2], acc[4 * j + 3]);
    }
}

extern "C" void kernel_launch(void* const* d_in, const int* in_sizes, int n_in,
                              void* d_out, int out_size, void* d_ws, size_t ws_size,
                              hipStream_t stream)
{
    const float* log_dt = (const float*)d_in[0];
    const float* B_real = (const float*)d_in[1];
    const float* B_imag = (const float*)d_in[2];
    const float* Cmat   = (const float*)d_in[3];
    // d_in[4] = Kc (unused by reference)
    const float* A_real = (const float*)d_in[5];
    const float* A_imag = (const float*)d_in[6];
    // d_in[7] = L (fixed 8192)
    float* out = (float*)d_out;

    dim3 grid(LVAL / (TPB * CHUNK), HN);   // (2, 512)
    s4d_main<<<grid, dim3(TPB), 0, stream>>>(log_dt, B_real, B_imag, Cmat,
                                             A_real, A_imag, out);
}

// Round 3
// 21.981 us; speedup vs baseline: 1.5524x; 1.5524x over previous
//
#include <hip/hip_runtime.h>
#include <math.h>

#define HN   512
#define N2M  32
#define LVAL 8192
#define CHUNK 16
#define TPB  256

// One block per (l-tile, h). First 32 threads compute per-mode params into LDS
// (packed as 2 float4 per mode), then every thread evaluates CHUNK consecutive
// l values for all 32 modes:
//   chunk start: exact |z|^l0 via exp2 + hi/lo-split revolution phase (raw
//   v_sin/v_cos, which take revolutions), then 2nd-order REAL recurrence
//   s_{l+1} = a*s_l + b*s_{l-1}, a=2Re(z), b=-|z|^2  (3 VALU ops per (n,l)).
__global__ __launch_bounds__(TPB) void s4d_main(
    const float* __restrict__ log_dt,
    const float* __restrict__ B_real,
    const float* __restrict__ B_imag,
    const float* __restrict__ Cmat,
    const float* __restrict__ A_real,
    const float* __restrict__ A_imag,
    float* __restrict__ out)
{
    __shared__ float4 sp4[N2M * 2];
    const int h = blockIdx.y;
    const int t = threadIdx.x;

    if (t < N2M) {
        const int idx = h * N2M + t;
        const float dt  = expf(log_dt[h]);
        const float Are = -expf(A_real[idx]) - 1e-6f;
        const float Aim = A_imag[idx];
        const float hdt = 0.5f * dt;
        // denom = 1 - dt*A/2 + 1e-6
        const float dre  = 1.0f - hdt * Are + 1e-6f;
        const float dim_ = -hdt * Aim;
        // num = 1 + dt*A/2
        const float nre = 1.0f + hdt * Are;
        const float nim = hdt * Aim;
        const float inv = 1.0f / (dre * dre + dim_ * dim_);
        // z = dtA
        const float zr = (nre * dre + nim * dim_) * inv;
        const float zi = (nim * dre - nre * dim_) * inv;
        // c2 = 2*C*dtB
        const float br = B_real[idx], bi = B_imag[idx];
        const float tbr = dt * ((br * dre + bi * dim_) * inv);
        const float tbi = dt * ((bi * dre - br * dim_) * inv);
        const float Cv = Cmat[idx];
        const float c2r = 2.0f * Cv * tbr;
        const float c2i = 2.0f * Cv * tbi;
        // recurrence coeffs + log-polar form
        const float r2 = zr * zr + zi * zi;
        const float a  = 2.0f * zr;
        const float b  = -r2;
        const float xl2 = 0.5f * log2f(r2);          // log2|z|
        const float phi = atan2f(zi, zr) * 0.15915494309189535f; // revolutions
        const float phi_hi = __uint_as_float(__float_as_uint(phi) & 0xFFFFE000u);
        const float phi_lo = phi - phi_hi;
        sp4[t * 2 + 0] = make_float4(a, b, xl2, zi);
        sp4[t * 2 + 1] = make_float4(phi_hi, phi_lo, c2r, c2i);
    }
    __syncthreads();

    const int l0 = blockIdx.x * (TPB * CHUNK) + t * CHUNK;
    const float l0f = (float)l0;

    float acc[CHUNK];
#pragma unroll
    for (int j = 0; j < CHUNK; ++j) acc[j] = 0.0f;

#pragma unroll 4
    for (int n = 0; n < N2M; ++n) {
        const float4 q0 = sp4[n * 2 + 0];   // a, b, log2|z|, zi
        const float4 q1 = sp4[n * 2 + 1];   // phi_hi, phi_lo, c2r, c2i

        // |z|^l0 = 2^(l0 * log2|z|)
        const float e = __builtin_amdgcn_exp2f(l0f * q0.z);
        // phase(l0) in revolutions, exactly range-reduced (l0*phi_hi exact)
        const float p   = l0f * q1.x;
        const float f1  = __builtin_amdgcn_fractf(p);
        const float rev = __builtin_amdgcn_fractf(fmaf(l0f, q1.y, f1));
        const float sn = __builtin_amdgcn_sinf(rev);   // v_sin_f32: revolutions
        const float cs = __builtin_amdgcn_cosf(rev);

        // u = c2 * z^l0
        const float ur = e * fmaf(q1.z, cs, -(q1.w * sn));
        const float ui = e * fmaf(q1.z, sn,  (q1.w * cs));

        // s0 = Re(u), s1 = Re(u*z)
        const float zr = 0.5f * q0.x;
        float s0 = ur;
        float s1 = fmaf(ur, zr, -(ui * q0.w));
        acc[0] += s0;
        acc[1] += s1;
#pragma unroll
        for (int j = 2; j < CHUNK; ++j) {
            const float s2 = fmaf(q0.x, s1, q0.y * s0);
            acc[j] += s2;
            s0 = s1;
            s1 = s2;
        }
    }

    float4* o = (float4*)(out + (size_t)h * LVAL + l0);
#pragma unroll
    for (int j = 0; j < CHUNK / 4; ++j) {
        o[j] = make_float4(acc[4 * j + 0], acc[4 * j + 1],
                           acc[4 * j + 2], acc[4 * j + 3]);
    }
}

extern "C" void kernel_launch(void* const* d_in, const int* in_sizes, int n_in,
                              void* d_out, int out_size, void* d_ws, size_t ws_size,
                              hipStream_t stream)
{
    const float* log_dt = (const float*)d_in[0];
    const float* B_real = (const float*)d_in[1];
    const float* B_imag = (const float*)d_in[2];
    const float* Cmat   = (const float*)d_in[3];
    // d_in[4] = Kc (unused by reference)
    const float* A_real = (const float*)d_in[5];
    const float* A_imag = (const float*)d_in[6];
    // d_in[7] = L (fixed 8192)
    float* out = (float*)d_out;

    dim3 grid(LVAL / (TPB * CHUNK), HN);   // (2, 512)
    s4d_main<<<grid, dim3(TPB), 0, stream>>>(log_dt, B_real, B_imag, Cmat,
                                             A_real, A_imag, out);
}

// Round 4
// 13.576 us; speedup vs baseline: 2.5134x; 1.6190x over previous
//
#include <hip/hip_runtime.h>
#include <math.h>

#define HN   512
#define N2M  32
#define LVAL 8192
#define TPB  256
#define STR  136   // f16 per LDS row (128 data + 8 pad); dword stride 68
#define STRD 68

typedef _Float16 f16x8 __attribute__((ext_vector_type(8)));
typedef float    f32x4 __attribute__((ext_vector_type(4)));

// Split x,y into f16 hi + f16 lo residual; store packed dwords (x in low half).
__device__ __forceinline__ void split_store(unsigned* dst_hi, unsigned* dst_lo,
                                            float x, float y) {
    const _Float16 hx = (_Float16)x, hy = (_Float16)y;
    const float lxf = x - (float)hx, lyf = y - (float)hy;
    const _Float16 lx = (_Float16)lxf, ly = (_Float16)lyf;
    const unsigned short ux = __builtin_bit_cast(unsigned short, hx);
    const unsigned short uy = __builtin_bit_cast(unsigned short, hy);
    const unsigned short vx = __builtin_bit_cast(unsigned short, lx);
    const unsigned short vy = __builtin_bit_cast(unsigned short, ly);
    *dst_hi = (unsigned)ux | ((unsigned)uy << 16);
    *dst_lo = (unsigned)vx | ((unsigned)vy << 16);
}

// Block = (l-half bx, head h). Stages:
//  1. t<32: per-mode params -> pm  (z, c2=2*C*dtB, log2|z|, phase hi/lo, z^64)
//  2. W table (j-major, 64 j x [hi(64)|lo(64)] k):  W[2n][j]=Re(z^j), W[2n+1][j]=-Im(z^j)
//  3. U table (m-major, 64 m x [hi|lo]):            U[m][2n]=Re(u), U[m][2n+1]=Im(u), u=c2*z^(64m+4096bx)
//  4. MFMA 16x16x32_f16: K = Uhi*Whi + Ulo*Whi + Uhi*Wlo  (split-f16 ~ f32 precision)
__global__ __launch_bounds__(TPB, 4) void s4d_mfma(
    const float* __restrict__ log_dt,
    const float* __restrict__ B_real,
    const float* __restrict__ B_imag,
    const float* __restrict__ Cmat,
    const float* __restrict__ A_real,
    const float* __restrict__ A_imag,
    float* __restrict__ out)
{
    __shared__ __align__(16) _Float16 shU[64 * STR];
    __shared__ __align__(16) _Float16 shW[64 * STR];
    __shared__ float pm[N2M][12];

    const int h  = blockIdx.y;
    const int bx = blockIdx.x;
    const int t  = threadIdx.x;

    // ---- Stage 1: per-mode params (verified path from R2 kernel) ----
    if (t < N2M) {
        const int idx = h * N2M + t;
        const float dt  = expf(log_dt[h]);
        const float Are = -expf(A_real[idx]) - 1e-6f;
        const float Aim = A_imag[idx];
        const float hdt = 0.5f * dt;
        const float dre  = 1.0f - hdt * Are + 1e-6f;
        const float dim_ = -hdt * Aim;
        const float nre = 1.0f + hdt * Are;
        const float nim = hdt * Aim;
        const float inv = 1.0f / (dre * dre + dim_ * dim_);
        const float zr = (nre * dre + nim * dim_) * inv;
        const float zi = (nim * dre - nre * dim_) * inv;
        const float br = B_real[idx], bi = B_imag[idx];
        const float tbr = dt * ((br * dre + bi * dim_) * inv);
        const float tbi = dt * ((bi * dre - br * dim_) * inv);
        const float Cv = Cmat[idx];
        const float c2r = 2.0f * Cv * tbr;
        const float c2i = 2.0f * Cv * tbi;
        const float r2  = zr * zr + zi * zi;
        const float xl2 = 0.5f * log2f(r2);                       // log2|z|
        const float phi = atan2f(zi, zr) * 0.15915494309189535f;  // revolutions
        const float ph  = __uint_as_float(__float_as_uint(phi) & 0xFFFFE000u);
        const float pl  = phi - ph;
        // z^64 (for U's m-recurrence)
        const float e64   = __builtin_amdgcn_exp2f(64.0f * xl2);
        const float rev64 = __builtin_amdgcn_fractf(
            fmaf(64.0f, pl, __builtin_amdgcn_fractf(64.0f * ph)));
        const float z64r = e64 * __builtin_amdgcn_cosf(rev64);
        const float z64i = e64 * __builtin_amdgcn_sinf(rev64);
        pm[t][0] = xl2; pm[t][1] = ph;  pm[t][2] = pl;
        pm[t][3] = c2r; pm[t][4] = c2i;
        pm[t][5] = zr;  pm[t][6] = zi;
        pm[t][7] = z64r; pm[t][8] = z64i;
    }
    __syncthreads();

    // ---- Stage 2: W table. thread -> (mode n = t>>3, j0 = (t&7)*8), 8 j's ----
    {
        const int n  = t >> 3;
        const int j0 = (t & 7) * 8;
        const float xl2 = pm[n][0], ph = pm[n][1], pl = pm[n][2];
        const float zr  = pm[n][5], zi = pm[n][6];
        const float j0f = (float)j0;
        const float e   = __builtin_amdgcn_exp2f(j0f * xl2);
        const float rev = __builtin_amdgcn_fractf(
            fmaf(j0f, pl, __builtin_amdgcn_fractf(j0f * ph)));
        float wr = e * __builtin_amdgcn_cosf(rev);
        float wi = e * __builtin_amdgcn_sinf(rev);
        unsigned* dw = (unsigned*)shW;
#pragma unroll
        for (int jj = 0; jj < 8; ++jj) {
            const int j = j0 + jj;
            split_store(dw + j * STRD + n, dw + j * STRD + 32 + n, wr, -wi);
            const float nwr = wr * zr - wi * zi;
            wi = fmaf(wr, zi, wi * zr);
            wr = nwr;
        }
    }

    // ---- Stage 3: U table. thread -> (mode n = t>>3, m0 = (t&7)*8), 8 m's ----
    {
        const int n  = t >> 3;
        const int m0 = (t & 7) * 8;
        const float xl2 = pm[n][0], ph = pm[n][1], pl = pm[n][2];
        const float c2r = pm[n][3], c2i = pm[n][4];
        const float z64r = pm[n][7], z64i = pm[n][8];
        const float l0f = (float)((bx << 12) + (m0 << 6));  // 64*(64*bx + m0): exact
        const float e   = __builtin_amdgcn_exp2f(l0f * xl2);
        const float rev = __builtin_amdgcn_fractf(
            fmaf(l0f, pl, __builtin_amdgcn_fractf(l0f * ph)));
        const float cs_ = __builtin_amdgcn_cosf(rev);
        const float sn_ = __builtin_amdgcn_sinf(rev);
        float ur = e * fmaf(c2r, cs_, -(c2i * sn_));
        float ui = e * fmaf(c2r, sn_, c2i * cs_);
        unsigned* dw = (unsigned*)shU;
#pragma unroll
        for (int mm = 0; mm < 8; ++mm) {
            const int m = m0 + mm;
            split_store(dw + m * STRD + n, dw + m * STRD + 32 + n, ur, ui);
            const float nur = ur * z64r - ui * z64i;
            ui = fmaf(ur, z64i, ui * z64r);
            ur = nur;
        }
    }
    __syncthreads();

    // ---- Stage 4: MFMA. wave w owns row-tile m in [16w,16w+16); jt = 0..3 ----
    const int w = t >> 6, lane = t & 63, g = lane >> 4, r = lane & 15;
    const _Float16* ua = shU + (w * 16 + r) * STR + g * 8;
    const f16x8 A0 = *(const f16x8*)(ua);        // U_hi k 0-31
    const f16x8 A1 = *(const f16x8*)(ua + 32);   // U_hi k 32-63
    const f16x8 A2 = *(const f16x8*)(ua + 64);   // U_lo k 0-31
    const f16x8 A3 = *(const f16x8*)(ua + 96);   // U_lo k 32-63
    float* outp = out + (size_t)h * LVAL + (bx << 12);
#pragma unroll
    for (int jt = 0; jt < 4; ++jt) {
        const _Float16* wb = shW + (jt * 16 + r) * STR + g * 8;
        const f16x8 B0 = *(const f16x8*)(wb);        // W_hi k 0-31
        const f16x8 B1 = *(const f16x8*)(wb + 32);   // W_hi k 32-63
        const f16x8 B2 = *(const f16x8*)(wb + 64);   // W_lo k 0-31
        const f16x8 B3 = *(const f16x8*)(wb + 96);   // W_lo k 32-63
        f32x4 acc = {0.f, 0.f, 0.f, 0.f};
        acc = __builtin_amdgcn_mfma_f32_16x16x32_f16(A0, B0, acc, 0, 0, 0);
        acc = __builtin_amdgcn_mfma_f32_16x16x32_f16(A1, B1, acc, 0, 0, 0);
        acc = __builtin_amdgcn_mfma_f32_16x16x32_f16(A2, B0, acc, 0, 0, 0);
        acc = __builtin_amdgcn_mfma_f32_16x16x32_f16(A3, B1, acc, 0, 0, 0);
        acc = __builtin_amdgcn_mfma_f32_16x16x32_f16(A0, B2, acc, 0, 0, 0);
        acc = __builtin_amdgcn_mfma_f32_16x16x32_f16(A1, B3, acc, 0, 0, 0);
        const int jcol = jt * 16 + r;
#pragma unroll
        for (int rr = 0; rr < 4; ++rr) {
            const int m_local = w * 16 + g * 4 + rr;   // C/D: row=(lane>>4)*4+reg
            outp[m_local * 64 + jcol] = acc[rr];
        }
    }
}

extern "C" void kernel_launch(void* const* d_in, const int* in_sizes, int n_in,
                              void* d_out, int out_size, void* d_ws, size_t ws_size,
                              hipStream_t stream)
{
    const float* log_dt = (const float*)d_in[0];
    const float* B_real = (const float*)d_in[1];
    const float* B_imag = (const float*)d_in[2];
    const float* Cmat   = (const float*)d_in[3];
    // d_in[4] = Kc (unused by reference)
    const float* A_real = (const float*)d_in[5];
    const float* A_imag = (const float*)d_in[6];
    // d_in[7] = L (fixed 8192)
    float* out = (float*)d_out;

    dim3 grid(2, HN);   // (l-half, head) = 1024 blocks
    s4d_mfma<<<grid, dim3(TPB), 0, stream>>>(log_dt, B_real, B_imag, Cmat,
                                             A_real, A_imag, out);
}